// Round 3
// baseline (696.419 us; speedup 1.0000x reference)
//
#include <hip/hip_runtime.h>

// Problem constants
#define B_Q   4096
#define E_DIM 512
#define N_C   2000
#define N_P   64000

// GEMM geometry: 256x256 tile, BK=64 (2 K-halves of 32), 8 waves (2M x 4N),
// 8-phase schedule, double-buffered 128 KiB LDS.  Persistent blocks: each of
// 250 blocks owns one 256-row W panel and sweeps all 16 column tiles; the
// staging pipeline is continuous across column boundaries (indexed by global
// k-tile g = col*8 + kt, g in [0,128)).
#define BM 256
#define BN 256
#define NG 128   // total k-tiles per block = 16 cols * 8

typedef __bf16 bf16x8 __attribute__((ext_vector_type(8)));
typedef float  f32x4  __attribute__((ext_vector_type(4)));

__device__ __forceinline__ unsigned short f2bf(float f) {
  unsigned u = __builtin_bit_cast(unsigned, f);
  u += 0x7fffu + ((u >> 16) & 1u);
  return (unsigned short)(u >> 16);
}

__device__ __forceinline__ void async_ld16(const void* g, void* l) {
  __builtin_amdgcn_global_load_lds(
      (const __attribute__((address_space(1))) void*)g,
      (__attribute__((address_space(3))) void*)l,
      16, 0, 0);
}

// ---------------------------------------------------------------------------
// Row L2-normalize fp32 -> bf16.  One block (128 threads) per 512-elem row.
// ---------------------------------------------------------------------------
__global__ __launch_bounds__(128) void norm_rows_kernel(
    const float* __restrict__ in, unsigned short* __restrict__ outbf)
{
  const int row = blockIdx.x;
  const int tid = threadIdx.x;
  const float4 v = *(const float4*)(in + (size_t)row * E_DIM + tid * 4);
  float ss = v.x*v.x + v.y*v.y + v.z*v.z + v.w*v.w;
  #pragma unroll
  for (int s = 1; s < 64; s <<= 1) ss += __shfl_xor(ss, s);
  __shared__ float partial[2];
  if ((tid & 63) == 0) partial[tid >> 6] = ss;
  __syncthreads();
  const float tot = partial[0] + partial[1];
  const float inv = 1.0f / fmaxf(sqrtf(tot), 1e-12f);
  ushort4 o;
  o.x = f2bf(v.x * inv); o.y = f2bf(v.y * inv);
  o.z = f2bf(v.z * inv); o.w = f2bf(v.w * inv);
  *(ushort4*)(outbf + (size_t)row * E_DIM + tid * 4) = o;
}

// ---------------------------------------------------------------------------
// LDS layout (bytes):  A[buf][h][row 0..255][chunk 0..3][16B]  base 0
//                      B[buf][h][row 0..255][chunk 0..3][16B]  base 65536
//   region(buf,h) = 16 KiB; buf stride 32768, h stride 16384.
//   chunk swizzle: LDS slot (row, cc) holds global 16B-chunk cc ^ ((row>>1)&3);
//   stager pre-swizzles the GLOBAL source chunk, LDS dest stays linear.
//
// Region staging ledger (iter g computes k-tile g from buf0 ph1-4, g+1 from
// buf1 ph5-8):
//   p1: A(buf1,h1,g+1)   p2: B(buf1,h1,g+1)
//   p3: A(buf0,h0,g+2)   p4: B(buf0,h0,g+2)
//   p5: A(buf0,h1,g+2)   p6: B(buf0,h1,g+2)
//   p7: A(buf1,h0,g+3)   p8: B(buf1,h0,g+3)
// vmcnt(8) after even-phase stage guarantees the region needed two phases
// later has landed.  Prologue: 12 loads, vmcnt(8).  Drain iter (g=126):
// stages only (1,1,127); waits 8/4/0.
// Column epilogues (shuffle-max + stores) sit between iterations; stores are
// younger than any guarded load, so the in-order vmcnt ledger stays valid.
// ---------------------------------------------------------------------------
#define WAITV(N) asm volatile("s_waitcnt vmcnt(" #N ")" ::: "memory")
#define SBAR     asm volatile("s_barrier" ::: "memory")

#define STAGE_A(BUF,H,G) do { \
  async_ld16(gA + ((G)&7)*64 + (H)*32,         smem + (BUF)*32768 + (H)*16384 + sdst); \
  async_ld16(gA + 65536 + ((G)&7)*64 + (H)*32, smem + (BUF)*32768 + (H)*16384 + sdst + 8192); \
} while(0)

#define STAGE_B(BUF,H,G) do { \
  async_ld16(gB + (size_t)((G)>>3)*131072 + ((G)&7)*64 + (H)*32, \
             smem + 65536 + (BUF)*32768 + (H)*16384 + sdst); \
  async_ld16(gB + (size_t)((G)>>3)*131072 + 65536 + ((G)&7)*64 + (H)*32, \
             smem + 65536 + (BUF)*32768 + (H)*16384 + sdst + 8192); \
} while(0)

#define PH(BUF,H,MH,RB, STAGE, WAIT) do { \
  if (RB) { \
    _Pragma("unroll") \
    for (int n = 0; n < 4; ++n) \
      bfr[n] = *(const bf16x8*)(pb + (BUF)*32768 + (H)*16384 + n*1024); \
  } \
  _Pragma("unroll") \
  for (int m = 0; m < 4; ++m) \
    afr[m] = *(const bf16x8*)(pa + (BUF)*32768 + (H)*16384 + ((MH)*4+m)*1024); \
  STAGE; \
  WAIT; \
  SBAR; \
  asm volatile("s_waitcnt lgkmcnt(0)" ::: "memory"); \
  __builtin_amdgcn_sched_barrier(0); \
  __builtin_amdgcn_s_setprio(1); \
  _Pragma("unroll") \
  for (int m = 0; m < 4; ++m) { \
    _Pragma("unroll") \
    for (int n = 0; n < 4; ++n) \
      acc[(MH)*4+m][n] = __builtin_amdgcn_mfma_f32_16x16x32_bf16( \
          afr[m], bfr[n], acc[(MH)*4+m][n], 0, 0, 0); \
  } \
  __builtin_amdgcn_s_setprio(0); \
  SBAR; \
} while(0)

__global__ __launch_bounds__(512, 2) void gemm_max_kernel(
    const unsigned short* __restrict__ wbf,   // [64000][512] bf16, normalized
    const unsigned short* __restrict__ dbf,   // [4096][512]  bf16, normalized
    float* __restrict__ out)                  // [2000][4096]
{
  extern __shared__ char smem[];              // 131072 B

  const int tid  = threadIdx.x;
  const int lane = tid & 63;
  const int wid  = tid >> 6;      // 0..7
  const int wr   = wid >> 2;      // 0..1  (128 rows each)
  const int wc   = wid & 3;       // 0..3  (64 cols each)

  const int rowBase = blockIdx.x * BM;   // 250 blocks, one W panel each

  // Staging: region = 256 rows x 32 shorts = 1024 x 16B chunks; thread t
  // handles chunks t (rows 0-127) and t+512 (rows 128-255).
  const int srow = tid >> 2;
  const int gch  = (tid & 3) ^ ((tid >> 3) & 3);   // pre-swizzled global chunk
  const unsigned short* gA = wbf + (size_t)(rowBase + srow) * E_DIM + gch * 8;
  const unsigned short* gB = dbf + (size_t)srow * E_DIM + gch * 8;
  const int sdst = tid * 16;      // linear LDS dest

  // Fragment read bases (swizzled chunk)
  const int r   = lane & 15;
  const int kg  = lane >> 4;
  const int swz = (kg ^ ((r >> 1) & 3)) * 16;
  const char* pa = smem + (wr * 128 + r) * 64 + swz;
  const char* pb = smem + 65536 + (wc * 64 + r) * 64 + swz;

  f32x4 acc[8][4];
  #pragma unroll
  for (int m = 0; m < 8; ++m)
    #pragma unroll
    for (int n = 0; n < 4; ++n)
      acc[m][n] = (f32x4){0.f, 0.f, 0.f, 0.f};
  bf16x8 afr[4], bfr[4];

  // Prologue: 12 loads, oldest 4 = tile0 h0 (needed by p1).
  STAGE_A(0,0,0); STAGE_B(0,0,0);
  STAGE_A(0,1,0); STAGE_B(0,1,0);
  STAGE_A(1,0,1); STAGE_B(1,0,1);
  WAITV(8);
  SBAR;

  const int classRowBase = blockIdx.x * 8;

  #pragma unroll 1
  for (int c = 0; c < 16; ++c) {
    #pragma unroll 1
    for (int ii = 0; ii < 4; ++ii) {
      const int g = c * 8 + ii * 2;
      if (g < 126) {
        PH(0,0,0,1, STAGE_A(1,1,g+1), (void)0);
        PH(0,0,1,0, STAGE_B(1,1,g+1), WAITV(8));
        PH(0,1,0,1, STAGE_A(0,0,g+2), (void)0);
        PH(0,1,1,0, STAGE_B(0,0,g+2), WAITV(8));
        PH(1,0,0,1, STAGE_A(0,1,g+2), (void)0);
        PH(1,0,1,0, STAGE_B(0,1,g+2), WAITV(8));
        PH(1,1,0,1, STAGE_A(1,0,g+3), (void)0);
        PH(1,1,1,0, STAGE_B(1,0,g+3), WAITV(8));
      } else {  // g == 126: drain
        PH(0,0,0,1, STAGE_A(1,1,127), (void)0);
        PH(0,0,1,0, STAGE_B(1,1,127), WAITV(8));
        PH(0,1,0,1, (void)0, (void)0);
        PH(0,1,1,0, (void)0, WAITV(4));
        PH(1,0,0,1, (void)0, (void)0);
        PH(1,0,1,0, (void)0, WAITV(0));
        PH(1,1,0,1, (void)0, (void)0);
        PH(1,1,1,0, (void)0, (void)0);
      }
    }

    // Column-c epilogue: per-class max.  Wave row = wr*128 + m*16 + kg*4 + j;
    // class within wave = m>>1 (32 rows).  Reduce m-pair x j, then across kg.
    {
      const int colBase = c * BN;
      #pragma unroll
      for (int q = 0; q < 4; ++q) {
        #pragma unroll
        for (int n = 0; n < 4; ++n) {
          float pm = -3.4e38f;
          #pragma unroll
          for (int j = 0; j < 4; ++j)
            pm = fmaxf(pm, fmaxf(acc[2*q][n][j], acc[2*q+1][n][j]));
          pm = fmaxf(pm, __shfl_xor(pm, 16));
          pm = fmaxf(pm, __shfl_xor(pm, 32));
          if (lane < 16)
            out[(size_t)(classRowBase + wr * 4 + q) * B_Q +
                colBase + wc * 64 + n * 16 + r] = pm;
        }
      }
      #pragma unroll
      for (int m = 0; m < 8; ++m)
        #pragma unroll
        for (int n = 0; n < 4; ++n)
          acc[m][n] = (f32x4){-3.4e38f, -3.4e38f, -3.4e38f, -3.4e38f} * 0.0f;
    }
  }
}

// ---------------------------------------------------------------------------
extern "C" void kernel_launch(void* const* d_in, const int* in_sizes, int n_in,
                              void* d_out, int out_size, void* d_ws, size_t ws_size,
                              hipStream_t stream) {
  const float* data = (const float*)d_in[0];   // [4096][512]
  const float* w1   = (const float*)d_in[1];   // [64000][512]
  float* out = (float*)d_out;                  // [2000][4096]

  unsigned short* wbf = (unsigned short*)d_ws;
  unsigned short* dbf = wbf + (size_t)N_P * E_DIM;

  (void)hipFuncSetAttribute((const void*)gemm_max_kernel,
      hipFuncAttributeMaxDynamicSharedMemorySize, 131072);

  norm_rows_kernel<<<N_P, 128, 0, stream>>>(w1, wbf);
  norm_rows_kernel<<<B_Q, 128, 0, stream>>>(data, dbf);
  gemm_max_kernel<<<N_P / BM, 512, 131072, stream>>>(wbf, dbf, out);
}

// Round 4
// 366.511 us; speedup vs baseline: 1.9001x; 1.9001x over previous
//
#include <hip/hip_runtime.h>

// Problem constants
#define B_Q   4096
#define E_DIM 512
#define N_C   2000
#define N_P   64000

// 256x256 tile, BK=64 (2 k-halves of 32), 8 waves (2M x 4N), 8-phase schedule,
// double-buffered 128 KiB LDS.  Persistent blocks: 250 blocks, one 256-row W
// panel each, sweeping 16 column tiles with the staging pipeline CONTINUOUS
// across column boundaries (global k-tile g = c*8 + kt, g in [0,128)).
// All stage offsets are compile-time literals (register diet vs round 3).
#define BM 256
#define BN 256

typedef __bf16 bf16x8 __attribute__((ext_vector_type(8)));
typedef float  f32x4  __attribute__((ext_vector_type(4)));

__device__ __forceinline__ unsigned short f2bf(float f) {
  unsigned u = __builtin_bit_cast(unsigned, f);
  u += 0x7fffu + ((u >> 16) & 1u);
  return (unsigned short)(u >> 16);
}

__device__ __forceinline__ void async_ld16(const void* g, void* l) {
  __builtin_amdgcn_global_load_lds(
      (const __attribute__((address_space(1))) void*)g,
      (__attribute__((address_space(3))) void*)l,
      16, 0, 0);
}

// ---------------------------------------------------------------------------
// Row L2-normalize fp32 -> bf16.  One block (128 threads) per 512-elem row.
// ---------------------------------------------------------------------------
__global__ __launch_bounds__(128) void norm_rows_kernel(
    const float* __restrict__ in, unsigned short* __restrict__ outbf)
{
  const int row = blockIdx.x;
  const int tid = threadIdx.x;
  const float4 v = *(const float4*)(in + (size_t)row * E_DIM + tid * 4);
  float ss = v.x*v.x + v.y*v.y + v.z*v.z + v.w*v.w;
  #pragma unroll
  for (int s = 1; s < 64; s <<= 1) ss += __shfl_xor(ss, s);
  __shared__ float partial[2];
  if ((tid & 63) == 0) partial[tid >> 6] = ss;
  __syncthreads();
  const float tot = partial[0] + partial[1];
  const float inv = 1.0f / fmaxf(sqrtf(tot), 1e-12f);
  ushort4 o;
  o.x = f2bf(v.x * inv); o.y = f2bf(v.y * inv);
  o.z = f2bf(v.z * inv); o.w = f2bf(v.w * inv);
  *(ushort4*)(outbf + (size_t)row * E_DIM + tid * 4) = o;
}

// ---------------------------------------------------------------------------
// LDS: A[buf][h][256 rows][4 x 16B] @0, B same @65536; region = 16 KiB.
// Chunk swizzle: slot (row,cc) holds global chunk cc ^ ((row>>1)&3); stager
// pre-swizzles the GLOBAL source chunk, LDS dest stays linear.
// Ledger per ii-block (computes k-tile g from buf0 ph1-4, g+1 from buf1 ph5-8):
//   p1 A(1,1,g+1)  p2 B(1,1,g+1)  p3 A(0,0,g+2)  p4 B(0,0,g+2)
//   p5 A(0,1,g+2)  p6 B(0,1,g+2)  p7 A(1,0,g+3)  p8 B(1,0,g+3)
// vmcnt(8) after even-phase stage guarantees the region needed two phases
// later has landed.  Epilogue stores add vmcnt entries; WAITV(8) then waits
// extra (stores are older than the 8 newest) -> still correct, once/column.
// ---------------------------------------------------------------------------
#define WAITV(N) asm volatile("s_waitcnt vmcnt(" #N ")" ::: "memory")
#define SBAR     asm volatile("s_barrier" ::: "memory")
#define NOPS     do {} while (0)

#define STAGE_A(BUF,H,KOFF) do { \
  async_ld16(gA + (KOFF)*64 + (H)*32,         smem + (BUF)*32768 + (H)*16384 + sdst); \
  async_ld16(gA + 65536 + (KOFF)*64 + (H)*32, smem + (BUF)*32768 + (H)*16384 + sdst + 8192); \
} while(0)

#define STAGE_B(BUF,H,PTR,KOFF) do { \
  async_ld16((PTR) + (KOFF)*64 + (H)*32,         smem + 65536 + (BUF)*32768 + (H)*16384 + sdst); \
  async_ld16((PTR) + 65536 + (KOFF)*64 + (H)*32, smem + 65536 + (BUF)*32768 + (H)*16384 + sdst + 8192); \
} while(0)

#define PH(BUF,H,MH,RB, STAGE, WAIT) do { \
  if (RB) { \
    _Pragma("unroll") \
    for (int n = 0; n < 4; ++n) \
      bfr[n] = *(const bf16x8*)(pb + (BUF)*32768 + (H)*16384 + n*1024); \
  } \
  _Pragma("unroll") \
  for (int m = 0; m < 4; ++m) \
    afr[m] = *(const bf16x8*)(pa + (BUF)*32768 + (H)*16384 + ((MH)*4+m)*1024); \
  STAGE; \
  WAIT; \
  SBAR; \
  asm volatile("s_waitcnt lgkmcnt(0)" ::: "memory"); \
  __builtin_amdgcn_sched_barrier(0); \
  __builtin_amdgcn_s_setprio(1); \
  _Pragma("unroll") \
  for (int m = 0; m < 4; ++m) { \
    _Pragma("unroll") \
    for (int n = 0; n < 4; ++n) \
      acc[(MH)*4+m][n] = __builtin_amdgcn_mfma_f32_16x16x32_bf16( \
          afr[m], bfr[n], acc[(MH)*4+m][n], 0, 0, 0); \
  } \
  __builtin_amdgcn_s_setprio(0); \
  SBAR; \
} while(0)

// One ii-block: k-tiles g (buf0) and g+1 (buf1); all offsets literal.
// K1 = (g+1)&7, K2 = (g+2)&7, K3 = (g+3)&7; PB23 = B col pointer for g+2,g+3.
#define IIBLK(K1,K2,K3, PB23) do { \
  PH(0,0,0,1, STAGE_A(1,1,K1),          NOPS); \
  PH(0,0,1,0, STAGE_B(1,1,gB,K1),       WAITV(8)); \
  PH(0,1,0,1, STAGE_A(0,0,K2),          NOPS); \
  PH(0,1,1,0, STAGE_B(0,0,PB23,K2),     WAITV(8)); \
  PH(1,0,0,1, STAGE_A(0,1,K2),          NOPS); \
  PH(1,0,1,0, STAGE_B(0,1,PB23,K2),     WAITV(8)); \
  PH(1,1,0,1, STAGE_A(1,0,K3),          NOPS); \
  PH(1,1,1,0, STAGE_B(1,0,PB23,K3),     WAITV(8)); \
} while(0)

#define EPILOGUE do { \
  _Pragma("unroll") \
  for (int q = 0; q < 4; ++q) { \
    _Pragma("unroll") \
    for (int n = 0; n < 4; ++n) { \
      float pm = -3.4e38f; \
      _Pragma("unroll") \
      for (int j = 0; j < 4; ++j) \
        pm = fmaxf(pm, fmaxf(acc[2*q][n][j], acc[2*q+1][n][j])); \
      pm = fmaxf(pm, __shfl_xor(pm, 16)); \
      pm = fmaxf(pm, __shfl_xor(pm, 32)); \
      if (lane < 16) outp[q * B_Q + n * 16] = pm; \
    } \
  } \
} while(0)

__global__ __launch_bounds__(512, 2) void gemm_max_kernel(
    const unsigned short* __restrict__ wbf,   // [64000][512] bf16, normalized
    const unsigned short* __restrict__ dbf,   // [4096][512]  bf16, normalized
    float* __restrict__ out)                  // [2000][4096]
{
  extern __shared__ char smem[];              // 131072 B

  const int tid  = threadIdx.x;
  const int lane = tid & 63;
  const int wid  = tid >> 6;      // 0..7
  const int wr   = wid >> 2;      // 0..1  (128 rows each)
  const int wc   = wid & 3;       // 0..3  (64 cols each)

  const int rowBase = blockIdx.x * BM;   // 250 blocks, one W panel each

  // Staging: region = 256 rows x 32 shorts = 1024 x 16B chunks; thread t
  // handles chunks t (rows 0-127) and t+512 (rows 128-255).
  const int srow = tid >> 2;
  const int gch  = (tid & 3) ^ ((tid >> 3) & 3);   // pre-swizzled global chunk
  const unsigned short* gA  = wbf + (size_t)(rowBase + srow) * E_DIM + gch * 8;
  const unsigned short* gB  = dbf + (size_t)srow * E_DIM + gch * 8;
  const unsigned short* gBn = gB + 131072;         // next column (256 rows)
  const int sdst = tid * 16;      // linear LDS dest

  // Fragment read bases (swizzled chunk)
  const int r   = lane & 15;
  const int kg  = lane >> 4;
  const int swz = (kg ^ ((r >> 1) & 3)) * 16;
  const char* pa = smem + (wr * 128 + r) * 64 + swz;
  const char* pb = smem + 65536 + (wc * 64 + r) * 64 + swz;

  float* outp = out + (size_t)(blockIdx.x * 8 + wr * 4) * B_Q + wc * 64 + r;

  f32x4 acc[8][4];
  #pragma unroll
  for (int m = 0; m < 8; ++m)
    #pragma unroll
    for (int n = 0; n < 4; ++n)
      acc[m][n] = (f32x4){0.f, 0.f, 0.f, 0.f};
  bf16x8 afr[4], bfr[4];

  // Prologue: 12 loads (tiles 0.h0, 0.h1, 1.h0), oldest 4 needed first.
  STAGE_A(0,0,0); STAGE_B(0,0,gB,0);
  STAGE_A(0,1,0); STAGE_B(0,1,gB,0);
  STAGE_A(1,0,1); STAGE_B(1,0,gB,1);
  WAITV(8);
  SBAR;

  #pragma unroll 1
  for (int c = 0; c < 15; ++c) {
    IIBLK(1,2,3, gB);
    IIBLK(3,4,5, gB);
    IIBLK(5,6,7, gB);
    IIBLK(7,0,1, gBn);           // g+2,g+3 wrap into next column's tiles 0,1
    EPILOGUE;
    #pragma unroll
    for (int m = 0; m < 8; ++m)
      #pragma unroll
      for (int n = 0; n < 4; ++n)
        acc[m][n] = (f32x4){0.f, 0.f, 0.f, 0.f};
    gB = gBn; gBn += 131072;
    outp += BN;
  }

  // Tail column (c = 15): 3 normal ii-blocks + drain block (g = 126).
  IIBLK(1,2,3, gB);
  IIBLK(3,4,5, gB);
  IIBLK(5,6,7, gB);
  PH(0,0,0,1, STAGE_A(1,1,7),    NOPS);
  PH(0,0,1,0, STAGE_B(1,1,gB,7), WAITV(8));
  PH(0,1,0,1, NOPS,              NOPS);
  PH(0,1,1,0, NOPS,              WAITV(4));
  PH(1,0,0,1, NOPS,              NOPS);
  PH(1,0,1,0, NOPS,              WAITV(0));
  PH(1,1,0,1, NOPS,              NOPS);
  PH(1,1,1,0, NOPS,              NOPS);
  EPILOGUE;
}

// ---------------------------------------------------------------------------
extern "C" void kernel_launch(void* const* d_in, const int* in_sizes, int n_in,
                              void* d_out, int out_size, void* d_ws, size_t ws_size,
                              hipStream_t stream) {
  const float* data = (const float*)d_in[0];   // [4096][512]
  const float* w1   = (const float*)d_in[1];   // [64000][512]
  float* out = (float*)d_out;                  // [2000][4096]

  unsigned short* wbf = (unsigned short*)d_ws;
  unsigned short* dbf = wbf + (size_t)N_P * E_DIM;

  (void)hipFuncSetAttribute((const void*)gemm_max_kernel,
      hipFuncAttributeMaxDynamicSharedMemorySize, 131072);

  norm_rows_kernel<<<N_P, 128, 0, stream>>>(w1, wbf);
  norm_rows_kernel<<<B_Q, 128, 0, stream>>>(data, dbf);
  gemm_max_kernel<<<N_P / BM, 512, 131072, stream>>>(wbf, dbf, out);
}